// Round 6
// baseline (23.685 us; speedup 1.0000x reference)
//
#include <hip/hip_runtime.h>

constexpr int T    = 512;
constexpr int C    = 512;
constexpr int HALF = 50;
constexpr int W    = 2 * HALF + 1;   // 101
constexpr int RPW  = 4;              // rows (t values) per wave
constexpr int WAVES = 4;             // waves per block

// R6 = R5 kernel, UNCHANGED, launched twice (diagnostic to separate fixed
// graph/launch overhead from true kernel time: dur6 - dur5 = kernel time).
__global__ __launch_bounds__(256, 4) void TimeAttention_33715493274067_kernel(
    const int*   __restrict__ concepts,   // [B,T]
    const int*   __restrict__ tgt_ts,     // [B,T]
    const int*   __restrict__ ctx_ts,     // [B,C]
    const int*   __restrict__ mask,       // [B,C]
    const float* __restrict__ emb,        // [V,W]
    const float* __restrict__ bias,       // [W]
    float*       __restrict__ out)        // [B,T,C]
{
    const int tid  = threadIdx.x;
    const int lane = tid & 63;
    const int g = __builtin_amdgcn_readfirstlane(blockIdx.x * WAVES + (tid >> 6));
    const int b   = g >> 7;               // T/RPW = 128 groups per b
    const int bt0 = b * T + (g & 127) * RPW;

    const int cbase0 = b * C + lane * 4;
    const int cbase1 = cbase0 + 256;
    const int4 ct0 = *(const int4*)(ctx_ts + cbase0);
    const int4 ct1 = *(const int4*)(ctx_ts + cbase1);
    const int4 mk0 = *(const int4*)(mask   + cbase0);
    const int4 mk1 = *(const int4*)(mask   + cbase1);

    const int4 cc  = *(const int4*)(concepts + bt0);
    const int4 tts = *(const int4*)(tgt_ts   + bt0);
    const int  ccr[RPW] = {cc.x, cc.y, cc.z, cc.w};
    const int  ttr[RPW] = {tts.x, tts.y, tts.z, tts.w};

    const float b0 = bias[0];
    const float bW = bias[W - 1];

    const int d[8]  = {ct0.x, ct0.y, ct0.z, ct0.w, ct1.x, ct1.y, ct1.z, ct1.w};
    const int mm[8] = {mk0.x, mk0.y, mk0.z, mk0.w, mk1.x, mk1.y, mk1.z, mk1.w};

    #pragma unroll
    for (int r = 0; r < RPW; ++r) {
        const float* erow = emb + (size_t)ccr[r] * W;
        const float eLo = __expf(erow[0]     + b0);
        const float eHi = __expf(erow[W - 1] + bW);
        const int   tt  = ttr[r];

        float e[8];
        float s = 0.0f;
        #pragma unroll
        for (int i = 0; i < 8; ++i) {
            const int idx = min(max(d[i] - tt, -HALF), HALF) + HALF;  // [0,100]
            float v;
            if (__builtin_expect((unsigned)(idx - 1) < 99u, 0)) {
                v = __expf(erow[idx] + bias[idx]);   // rare interior (~0.1%)
            } else {
                v = idx ? eHi : eLo;
            }
            e[i] = mm[i] ? 0.0f : v;                 // masked -> exactly 0
            s += e[i];
        }

        #pragma unroll
        for (int o = 1; o < 64; o <<= 1) s += __shfl_xor(s, o, 64);
        const float inv = __builtin_amdgcn_rcpf(s);

        float4 o0 = {e[0] * inv, e[1] * inv, e[2] * inv, e[3] * inv};
        float4 o1 = {e[4] * inv, e[5] * inv, e[6] * inv, e[7] * inv};
        float* obase = out + (size_t)(bt0 + r) * C;
        *(float4*)(obase + lane * 4)       = o0;
        *(float4*)(obase + 256 + lane * 4) = o1;
    }
}

extern "C" void kernel_launch(void* const* d_in, const int* in_sizes, int n_in,
                              void* d_out, int out_size, void* d_ws, size_t ws_size,
                              hipStream_t stream) {
    const int*   concepts = (const int*)  d_in[0];
    const int*   tgt_ts   = (const int*)  d_in[1];
    const int*   ctx_ts   = (const int*)  d_in[2];
    const int*   mask     = (const int*)  d_in[3];
    const float* emb      = (const float*)d_in[4];
    const float* bias     = (const float*)d_in[5];
    float*       out      = (float*)      d_out;

    const int n_bt = in_sizes[0];                    // B*T = 16384
    const int grid = n_bt / (RPW * WAVES);           // 1024 blocks

    // DIAGNOSTIC: two identical launches. Deterministic (2nd overwrites the
    // same values). Kernel-time K = dur(this round) - dur(last round).
    TimeAttention_33715493274067_kernel<<<grid, 256, 0, stream>>>(
        concepts, tgt_ts, ctx_ts, mask, emb, bias, out);
    TimeAttention_33715493274067_kernel<<<grid, 256, 0, stream>>>(
        concepts, tgt_ts, ctx_ts, mask, emb, bias, out);
}

// Round 7
// 13.937 us; speedup vs baseline: 1.6994x; 1.6994x over previous
//
#include <hip/hip_runtime.h>

constexpr int T    = 512;
constexpr int C    = 512;
constexpr int HALF = 50;
constexpr int W    = 2 * HALF + 1;   // 101
constexpr int RPW  = 2;              // rows (t values) per wave
constexpr int WAVES = 4;             // waves per block

// 64-lane f32 sum reduction in pure VALU via DPP (no LDS/bpermute):
// row_shr 1/2/4/8 accumulate within each 16-lane row; row_bcast:15/31 fold
// rows; lane 63 holds the total, broadcast via readlane.
__device__ __forceinline__ float wave_reduce_sum(float x) {
    union { float f; int i; } u, t;
    u.f = x; t.i = __builtin_amdgcn_update_dpp(0, u.i, 0x111, 0xf, 0xf, true); x += t.f; // row_shr:1
    u.f = x; t.i = __builtin_amdgcn_update_dpp(0, u.i, 0x112, 0xf, 0xf, true); x += t.f; // row_shr:2
    u.f = x; t.i = __builtin_amdgcn_update_dpp(0, u.i, 0x114, 0xf, 0xf, true); x += t.f; // row_shr:4
    u.f = x; t.i = __builtin_amdgcn_update_dpp(0, u.i, 0x118, 0xf, 0xf, true); x += t.f; // row_shr:8
    u.f = x; t.i = __builtin_amdgcn_update_dpp(0, u.i, 0x142, 0xf, 0xf, true); x += t.f; // row_bcast:15
    u.f = x; t.i = __builtin_amdgcn_update_dpp(0, u.i, 0x143, 0xf, 0xf, true); x += t.f; // row_bcast:31
    union { float f; int i; } r;
    r.i = __builtin_amdgcn_readlane(__builtin_bit_cast(int, x), 63);
    return r.f;
}

__global__ __launch_bounds__(256, 4) void TimeAttention_33715493274067_kernel(
    const int*   __restrict__ concepts,   // [B,T]
    const int*   __restrict__ tgt_ts,     // [B,T]
    const int*   __restrict__ ctx_ts,     // [B,C]
    const int*   __restrict__ mask,       // [B,C]
    const float* __restrict__ emb,        // [V,W]
    const float* __restrict__ bias,       // [W]
    float*       __restrict__ out)        // [B,T,C]
{
    const int tid  = threadIdx.x;
    const int lane = tid & 63;
    const int g = __builtin_amdgcn_readfirstlane(blockIdx.x * WAVES + (tid >> 6));
    const int b   = g >> 8;               // T/RPW = 256 groups per b
    const int bt0 = b * T + (g & 255) * RPW;

    // Per-lane context loads (shared by both rows): contiguous 1KB/instr.
    const int cbase0 = b * C + lane * 4;
    const int cbase1 = cbase0 + 256;
    const int4 ct0 = *(const int4*)(ctx_ts + cbase0);
    const int4 ct1 = *(const int4*)(ctx_ts + cbase1);
    const int4 mk0 = *(const int4*)(mask   + cbase0);
    const int4 mk1 = *(const int4*)(mask   + cbase1);

    const int2 cc  = *(const int2*)(concepts + bt0);   // uniform -> s_load
    const int2 tts = *(const int2*)(tgt_ts   + bt0);
    const int  ccr[RPW] = {cc.x, cc.y};
    const int  ttr[RPW] = {tts.x, tts.y};

    const float b0 = bias[0];
    const float bW = bias[W - 1];

    const int d[8]  = {ct0.x, ct0.y, ct0.z, ct0.w, ct1.x, ct1.y, ct1.z, ct1.w};
    const int mm[8] = {mk0.x, mk0.y, mk0.z, mk0.w, mk1.x, mk1.y, mk1.z, mk1.w};

    #pragma unroll
    for (int r = 0; r < RPW; ++r) {
        const float* erow = emb + (size_t)ccr[r] * W;
        const float eLo = __expf(erow[0]     + b0);
        const float eHi = __expf(erow[W - 1] + bW);
        const int   tt  = ttr[r];

        float e[8];
        float s = 0.0f;
        #pragma unroll
        for (int i = 0; i < 8; ++i) {
            const int idx = min(max(d[i] - tt, -HALF), HALF) + HALF;  // [0,100]
            float v;
            if (__builtin_expect((unsigned)(idx - 1) < 99u, 0)) {
                v = __expf(erow[idx] + bias[idx]);   // rare interior (~0.1%)
            } else {
                v = idx ? eHi : eLo;
            }
            e[i] = mm[i] ? 0.0f : v;                 // masked -> exactly 0
            s += e[i];
        }

        const float inv = __builtin_amdgcn_rcpf(wave_reduce_sum(s));

        float4 o0 = {e[0] * inv, e[1] * inv, e[2] * inv, e[3] * inv};
        float4 o1 = {e[4] * inv, e[5] * inv, e[6] * inv, e[7] * inv};
        float* obase = out + (size_t)(bt0 + r) * C;
        *(float4*)(obase + lane * 4)       = o0;     // contiguous 1KB/instr
        *(float4*)(obase + 256 + lane * 4) = o1;
    }
}

extern "C" void kernel_launch(void* const* d_in, const int* in_sizes, int n_in,
                              void* d_out, int out_size, void* d_ws, size_t ws_size,
                              hipStream_t stream) {
    const int*   concepts = (const int*)  d_in[0];
    const int*   tgt_ts   = (const int*)  d_in[1];
    const int*   ctx_ts   = (const int*)  d_in[2];
    const int*   mask     = (const int*)  d_in[3];
    const float* emb      = (const float*)d_in[4];
    const float* bias     = (const float*)d_in[5];
    float*       out      = (float*)      d_out;

    const int n_bt = in_sizes[0];                    // B*T = 16384
    const int grid = n_bt / (RPW * WAVES);           // 2048 blocks
    TimeAttention_33715493274067_kernel<<<grid, 256, 0, stream>>>(
        concepts, tgt_ts, ctx_ts, mask, emb, bias, out);
}

// Round 9
// 12.100 us; speedup vs baseline: 1.9574x; 1.1518x over previous
//
#include <hip/hip_runtime.h>

constexpr int T    = 512;
constexpr int C    = 512;
constexpr int HALF = 50;
constexpr int W    = 2 * HALF + 1;   // 101
constexpr int RPW  = 2;              // rows (t values) per wave
constexpr int WAVES = 4;             // waves per block

typedef float f32x4 __attribute__((ext_vector_type(4)));  // native vec for nt store

// R8' = R7 + NONTEMPORAL float4 stores (bypass L2 write-allocate: the 33.5MB
// output stream ~equals aggregate L2, so regular stores evict the hot
// ctx/mask/emb read set; nt stores stream to HBM and leave L2 for reads).
__device__ __forceinline__ float wave_reduce_sum(float x) {
    union { float f; int i; } u, t;
    u.f = x; t.i = __builtin_amdgcn_update_dpp(0, u.i, 0x111, 0xf, 0xf, true); x += t.f; // row_shr:1
    u.f = x; t.i = __builtin_amdgcn_update_dpp(0, u.i, 0x112, 0xf, 0xf, true); x += t.f; // row_shr:2
    u.f = x; t.i = __builtin_amdgcn_update_dpp(0, u.i, 0x114, 0xf, 0xf, true); x += t.f; // row_shr:4
    u.f = x; t.i = __builtin_amdgcn_update_dpp(0, u.i, 0x118, 0xf, 0xf, true); x += t.f; // row_shr:8
    u.f = x; t.i = __builtin_amdgcn_update_dpp(0, u.i, 0x142, 0xf, 0xf, true); x += t.f; // row_bcast:15
    u.f = x; t.i = __builtin_amdgcn_update_dpp(0, u.i, 0x143, 0xf, 0xf, true); x += t.f; // row_bcast:31
    union { float f; int i; } r;
    r.i = __builtin_amdgcn_readlane(__builtin_bit_cast(int, x), 63);
    return r.f;
}

__global__ __launch_bounds__(256, 4) void TimeAttention_33715493274067_kernel(
    const int*   __restrict__ concepts,   // [B,T]
    const int*   __restrict__ tgt_ts,     // [B,T]
    const int*   __restrict__ ctx_ts,     // [B,C]
    const int*   __restrict__ mask,       // [B,C]
    const float* __restrict__ emb,        // [V,W]
    const float* __restrict__ bias,       // [W]
    float*       __restrict__ out)        // [B,T,C]
{
    const int tid  = threadIdx.x;
    const int lane = tid & 63;
    const int g = __builtin_amdgcn_readfirstlane(blockIdx.x * WAVES + (tid >> 6));
    const int b   = g >> 8;               // T/RPW = 256 groups per b
    const int bt0 = b * T + (g & 255) * RPW;

    const int cbase0 = b * C + lane * 4;
    const int cbase1 = cbase0 + 256;
    const int4 ct0 = *(const int4*)(ctx_ts + cbase0);
    const int4 ct1 = *(const int4*)(ctx_ts + cbase1);
    const int4 mk0 = *(const int4*)(mask   + cbase0);
    const int4 mk1 = *(const int4*)(mask   + cbase1);

    const int2 cc  = *(const int2*)(concepts + bt0);   // uniform -> s_load
    const int2 tts = *(const int2*)(tgt_ts   + bt0);
    const int  ccr[RPW] = {cc.x, cc.y};
    const int  ttr[RPW] = {tts.x, tts.y};

    const float b0 = bias[0];
    const float bW = bias[W - 1];

    const int d[8]  = {ct0.x, ct0.y, ct0.z, ct0.w, ct1.x, ct1.y, ct1.z, ct1.w};
    const int mm[8] = {mk0.x, mk0.y, mk0.z, mk0.w, mk1.x, mk1.y, mk1.z, mk1.w};

    #pragma unroll
    for (int r = 0; r < RPW; ++r) {
        const float* erow = emb + (size_t)ccr[r] * W;
        const float eLo = __expf(erow[0]     + b0);
        const float eHi = __expf(erow[W - 1] + bW);
        const int   tt  = ttr[r];

        float e[8];
        float s = 0.0f;
        #pragma unroll
        for (int i = 0; i < 8; ++i) {
            const int idx = min(max(d[i] - tt, -HALF), HALF) + HALF;  // [0,100]
            float v;
            if (__builtin_expect((unsigned)(idx - 1) < 99u, 0)) {
                v = __expf(erow[idx] + bias[idx]);   // rare interior (~0.1%)
            } else {
                v = idx ? eHi : eLo;
            }
            e[i] = mm[i] ? 0.0f : v;                 // masked -> exactly 0
            s += e[i];
        }

        const float inv = __builtin_amdgcn_rcpf(wave_reduce_sum(s));

        f32x4 o0 = {e[0] * inv, e[1] * inv, e[2] * inv, e[3] * inv};
        f32x4 o1 = {e[4] * inv, e[5] * inv, e[6] * inv, e[7] * inv};
        float* obase = out + (size_t)(bt0 + r) * C;
        // Nontemporal: stream past L2 (output has zero reuse).
        __builtin_nontemporal_store(o0, (f32x4*)(obase + lane * 4));
        __builtin_nontemporal_store(o1, (f32x4*)(obase + 256 + lane * 4));
    }
}

extern "C" void kernel_launch(void* const* d_in, const int* in_sizes, int n_in,
                              void* d_out, int out_size, void* d_ws, size_t ws_size,
                              hipStream_t stream) {
    const int*   concepts = (const int*)  d_in[0];
    const int*   tgt_ts   = (const int*)  d_in[1];
    const int*   ctx_ts   = (const int*)  d_in[2];
    const int*   mask     = (const int*)  d_in[3];
    const float* emb      = (const float*)d_in[4];
    const float* bias     = (const float*)d_in[5];
    float*       out      = (float*)      d_out;

    const int n_bt = in_sizes[0];                    // B*T = 16384
    const int grid = n_bt / (RPW * WAVES);           // 2048 blocks
    TimeAttention_33715493274067_kernel<<<grid, 256, 0, stream>>>(
        concepts, tgt_ts, ctx_ts, mask, emb, bias, out);
}